// Round 1
// 1222.804 us; speedup vs baseline: 1.0281x; 1.0281x over previous
//
#include <hip/hip_runtime.h>
#include <stdint.h>

// ---------------- types / helpers ----------------
typedef __attribute__((ext_vector_type(4))) float  fx4;
typedef __attribute__((ext_vector_type(8))) short  bs8;

union Frag8 { bs8 s; unsigned u[4]; };

__device__ __forceinline__ unsigned short f2b(float f){
  union { float f; unsigned u; } v; v.f = f;
  unsigned r = (v.u + 0x7FFFu + ((v.u >> 16) & 1u)) >> 16;
  return (unsigned short)r;
}
__device__ __forceinline__ float b2f(unsigned short s){
  union { unsigned u; float f; } v; v.u = ((unsigned)s) << 16;
  return v.f;
}
__device__ __forceinline__ unsigned pack2(float a, float b){
  return (unsigned)f2b(a) | ((unsigned)f2b(b) << 16);
}

__device__ __forceinline__ float blk_sum(float v, float* scr, int t){
#pragma unroll
  for (int i = 1; i < 64; i <<= 1) v += __shfl_xor(v, i, 64);
  __syncthreads();
  if ((t & 63) == 0) scr[t >> 6] = v;
  __syncthreads();
  return scr[0] + scr[1] + scr[2] + scr[3];
}

// ---------------- P1: LN of the two query vectors (grid=2) ----------------
__global__ __launch_bounds__(256) void k_lnvec(
    const float* in0, const float* g0, const float* b0, float* out0,
    const float* in1, const float* g1, const float* b1, float* out1)
{
  __shared__ float scr[4];
  const float* in = blockIdx.x ? in1 : in0;
  const float* g  = blockIdx.x ? g1  : g0;
  const float* bb = blockIdx.x ? b1  : b0;
  float* out      = blockIdx.x ? out1 : out0;
  int t = threadIdx.x;
  float4 v = *(const float4*)(in + t*4);
  float s = blk_sum(v.x+v.y+v.z+v.w, scr, t);
  float mean = s * (1.0f/1024.0f);
  float4 d; d.x=v.x-mean; d.y=v.y-mean; d.z=v.z-mean; d.w=v.w-mean;
  float ss = blk_sum(d.x*d.x+d.y*d.y+d.z*d.z+d.w*d.w, scr, t);
  float rs = rsqrtf(ss*(1.0f/1024.0f) + 1e-5f);
  float4 gv = *(const float4*)(g + t*4);
  float4 bv = *(const float4*)(bb + t*4);
  float4 o; o.x=d.x*rs*gv.x+bv.x; o.y=d.y*rs*gv.y+bv.y; o.z=d.z*rs*gv.z+bv.z; o.w=d.w*rs*gv.w+bv.w;
  *(float4*)(out + t*4) = o;
}

// ---------------- P2: qh = q @ W[:, :1024] + b (grid=64; 32 per set) ----------------
__global__ __launch_bounds__(256) void k_gemv(
    const float* q0, const float* W0, const float* bias0, float* out0,
    const float* q1, const float* W1, const float* bias1, float* out1)
{
  int blk = blockIdx.x;
  int sel = blk >= 32;
  const float* qv = sel ? q1 : q0;
  const float* W  = sel ? W1 : W0;
  const float* bi = sel ? bias1 : bias0;
  float* ov       = sel ? out1 : out0;
  int j0 = (blk & 31) * 32;
  int t = threadIdx.x;
  int jl = t >> 3, l8 = t & 7;
  int j = j0 + jl;
  const float* Wc = W + j;
  float s = 0.f;
  for (int i = 0; i < 128; i++){
    int f = l8*128 + i;
    s += qv[f] * Wc[(long)f*3072];
  }
  s += __shfl_xor(s, 1, 64); s += __shfl_xor(s, 2, 64); s += __shfl_xor(s, 4, 64);
  if (l8 == 0) ov[j] = s + bi[j];
}

// ---------------- P3: weff (MFMA-B fragment order, bf16) + ceff (grid=128) ----------------
__global__ __launch_bounds__(256) void k_weff(
    const float* qh0, const float* W0, const float* bv0, unsigned short* outB0, float* ce0,
    const float* qh1, const float* W1, const float* bv1, unsigned short* outB1, float* ce1)
{
  int blk = blockIdx.x; int sel = blk >= 64; int fb = blk & 63;
  const float* qs = sel ? qh1 : qh0;
  const float* W  = sel ? W1  : W0;
  const float* bv = sel ? bv1 : bv0;
  unsigned short* oB = sel ? outB1 : outB0;
  float* ce = sel ? ce1 : ce0;
  int t = threadIdx.x; int h = t & 15, fl = t >> 4;
  int f = fb*16 + fl;
  const float* Wr = W + (long)f*3072 + 1024 + h*64;
  const float* qr = qs + h*64;
  float s = 0.f;
#pragma unroll 8
  for (int d = 0; d < 64; d++) s += Wr[d]*qr[d];
  int idx = (f>>5)*512 + ((f>>3)&3)*128 + h*8 + (f&7);
  oB[idx] = f2b(s);
  if (fb == 0 && t < 16){
    float c = 0.f;
    for (int d = 0; d < 64; d++) c += bv[1024 + t*64 + d]*qs[t*64+d];
    ce[t] = c;
  }
}

// ---------------- P4: transpose+cvt fp32[K][N] -> bf16[N][K] (5 segments) ----------------
__global__ __launch_bounds__(256) void k_transpose(
    const float* inA, long strA, unsigned short* outA, int cntA,
    const float* inB, long strB, unsigned short* outB, int cntB,
    const float* inC, long strC, unsigned short* outC, int cntC,
    const float* inD, long strD, unsigned short* outD, int cntD,
    const float* inE, long strE, unsigned short* outE, int cntE)
{
  int id = blockIdx.x;
  const float* in; long str; unsigned short* out;
  if (id < cntA){ in=inA; str=strA; out=outA; }
  else { id -= cntA;
    if (id < cntB){ in=inB; str=strB; out=outB; }
    else { id -= cntB;
      if (id < cntC){ in=inC; str=strC; out=outC; }
      else { id -= cntC;
        if (id < cntD){ in=inD; str=strD; out=outD; }
        else { id -= cntD; in=inE; str=strE; out=outE; }
      }
    }
  }
  int kt = id & 31, nt = id >> 5;
  __shared__ __align__(16) unsigned short tile[32][33];
  int t = threadIdx.x;
  int r = t >> 3, c4 = (t & 7)*4;
  float4 v = *(const float4*)(in + (long)(kt*32 + r)*str + nt*32 + c4);
  tile[c4+0][r] = f2b(v.x); tile[c4+1][r] = f2b(v.y);
  tile[c4+2][r] = f2b(v.z); tile[c4+3][r] = f2b(v.w);
  __syncthreads();
  int n = t >> 3, k4 = (t & 7)*4;
  ushort4 o; o.x = tile[n][k4]; o.y = tile[n][k4+1]; o.z = tile[n][k4+2]; o.w = tile[n][k4+3];
  *(ushort4*)(out + (long)(nt*32 + n)*1024 + kt*32 + k4) = o;
}

// ---------------- K1: per-(b,p) scores(MFMA)+softmax+ctx(MFMA) ----------------
// Phase 1: all 4 waves; wave-pairs split the K range (kk halves), partials in Sp[2].
// Phase 3: ctx[h][f] = sum_ch attn[ch][h]*tok[ch][f] as 16x16x32 MFMA per f-tile,
//          ch zero-padded 18->32 in registers; attn split hi+lo bf16 for precision.
// tok store/read uses a 16-half XOR swizzle keyed on (ch>>3)&1 to break the
// q-group bank collision (row stride 1032 halves => 8-row offset is bank-aligned).
__global__ __launch_bounds__(256) void k1_attn(
    const float* __restrict__ x,
    const unsigned short* __restrict__ weffB, const float* __restrict__ ceff,
    unsigned short* __restrict__ ctx, int bp0)
{
  __shared__ __align__(16) unsigned short tok[18*1032];   // bf16 tokens, row stride 1032
  __shared__ float Sp[2][18*16];
  __shared__ float attn[18*16];
  int bp = bp0 + blockIdx.x;
  int b = bp >> 6, p = bp & 63;
  int t = threadIdx.x;
  int w = t >> 6, l = t & 63, q = l >> 4, l16 = l & 15;
  int half = w >> 1, wr = w & 1;

  {
    int mlog = wr*16 + l16;
    int m = mlog > 17 ? 17 : mlog;
    const float* xrow = x + (((long)b*18 + m)*64 + p)*1024;
    bool store = (wr == 0) || (l16 < 2);
    int msw = ((m >> 3) & 1) << 4;
    fx4 acc = {0.f,0.f,0.f,0.f};
    int kk0 = half*16;
#pragma unroll 4
    for (int kk = kk0; kk < kk0+16; kk++){
      int f0 = kk*32 + q*8;
      float4 a0 = *(const float4*)(xrow + f0);
      float4 a1 = *(const float4*)(xrow + f0 + 4);
      Frag8 af;
      af.u[0] = pack2(a0.x,a0.y); af.u[1] = pack2(a0.z,a0.w);
      af.u[2] = pack2(a1.x,a1.y); af.u[3] = pack2(a1.z,a1.w);
      bs8 bf = *(const bs8*)(weffB + (kk*64 + l)*8);
      acc = __builtin_amdgcn_mfma_f32_16x16x32_bf16(af.s, bf, acc, 0, 0, 0);
      if (store) *(bs8*)(&tok[m*1032 + (f0 ^ msw)]) = af.s;
    }
#pragma unroll
    for (int i = 0; i < 4; i++){
      int r = wr*16 + q*4 + i;
      if (r < 18) Sp[half][r*16 + l16] = acc[i];
    }
  }
  __syncthreads();
  if (t < 16){
    float cf = ceff[t];
    float sv[18];
    float mx = -1e30f;
#pragma unroll
    for (int k = 0; k < 18; k++){
      float s = (Sp[0][k*16+t] + Sp[1][k*16+t] + cf) * 0.125f;
      sv[k] = s; mx = fmaxf(mx, s);
    }
    float sm = 0.f;
#pragma unroll
    for (int k = 0; k < 18; k++){ float e = expf(sv[k]-mx); sv[k] = e; sm += e; }
    float inv = 1.f/sm;
#pragma unroll
    for (int k = 0; k < 18; k++) attn[k*16+t] = sv[k]*inv;
  }
  __syncthreads();

  // B fragments (attn hi + lo residual), built once; zero for ch >= 18
  Frag8 Bhi, Blo;
#pragma unroll
  for (int jj = 0; jj < 4; jj++){
    int c0 = q*8 + jj*2, c1 = c0 + 1;
    float a0 = (c0 < 18) ? attn[c0*16 + l16] : 0.f;
    float a1 = (c1 < 18) ? attn[c1*16 + l16] : 0.f;
    unsigned short h0 = f2b(a0), h1 = f2b(a1);
    float r0 = a0 - b2f(h0), r1 = a1 - b2f(h1);
    Bhi.u[jj] = (unsigned)h0 | ((unsigned)h1 << 16);
    Blo.u[jj] = pack2(r0, r1);
  }
  // 16 f-tiles per wave: D[f_local][h] = sum_ch tok[ch][Tb+f_local]*attn[ch][h]
  unsigned short* crow = ctx + ((long)blockIdx.x*16 + l16)*1024 + q*4;
  int Tbase = w*256;
#pragma unroll 4
  for (int tt = 0; tt < 16; tt++){
    int Tb = Tbase + tt*16;
    int fA = Tb + l16;
    Frag8 A;
#pragma unroll
    for (int jj = 0; jj < 4; jj++){
      int c0 = q*8 + jj*2, c1 = c0 + 1;
      int c0c = c0 > 17 ? 17 : c0, c1c = c1 > 17 ? 17 : c1;
      unsigned v0 = tok[c0c*1032 + (fA ^ (((c0c>>3)&1)<<4))];
      unsigned v1 = tok[c1c*1032 + (fA ^ (((c1c>>3)&1)<<4))];
      if (c0 > 17) v0 = 0;
      if (c1 > 17) v1 = 0;
      A.u[jj] = v0 | (v1 << 16);
    }
    fx4 acc = {0.f,0.f,0.f,0.f};
    acc = __builtin_amdgcn_mfma_f32_16x16x32_bf16(A.s, Bhi.s, acc, 0, 0, 0);
    acc = __builtin_amdgcn_mfma_f32_16x16x32_bf16(A.s, Blo.s, acc, 0, 0, 0);
    uint2 o = make_uint2(pack2(acc[0],acc[1]), pack2(acc[2],acc[3]));
    *(uint2*)(crow + Tb) = o;
  }
}

// ---------------- generic bf16 GEMM: C[128 x 64/block] = A @ BT^T + bias ----------------
// A: bf16, row r at A + r*strideA + blockIdx.y*colAstep, K contiguous
// BT: bf16 [n][k] rows; block nb uses rows nb*64..+63
__global__ __launch_bounds__(256) void k_gemm(
    const unsigned short* __restrict__ A, long strideA, long colAstep,
    const unsigned short* __restrict__ BT, int Kfull,
    const float* __restrict__ bias,
    void* __restrict__ Cout, long strideC, int outBf16, int doGelu, int K)
{
  __shared__ __align__(16) unsigned short As[128*72];
  __shared__ __align__(16) unsigned short Bs[64*72];
  int t = threadIdx.x;
  int w = t >> 6, l = t & 63, q = l >> 4, l16 = l & 15;
  long mbase = (long)blockIdx.x * 128;
  int nb = blockIdx.y;
  const unsigned short* Ab = A + mbase*strideA + (long)nb*colAstep;
  const unsigned short* Bb = BT + (long)nb*64*Kfull;
  fx4 acc[2][4];
#pragma unroll
  for (int mf = 0; mf < 2; mf++)
#pragma unroll
    for (int nf = 0; nf < 4; nf++) acc[mf][nf] = (fx4){0.f,0.f,0.f,0.f};

  int ar = t >> 1, ac = (t & 1)*32;
  int bn = t >> 2, bc = (t & 3)*16;

  for (int k0 = 0; k0 < K; k0 += 64){
    const unsigned short* asrc = Ab + (long)ar*strideA + k0 + ac;
    uint4 av0 = *(const uint4*)(asrc);
    uint4 av1 = *(const uint4*)(asrc + 8);
    uint4 av2 = *(const uint4*)(asrc + 16);
    uint4 av3 = *(const uint4*)(asrc + 24);
    const unsigned short* bsrc = Bb + (long)bn*Kfull + k0 + bc;
    uint4 bv0 = *(const uint4*)(bsrc);
    uint4 bv1 = *(const uint4*)(bsrc + 8);
    __syncthreads();
    *(uint4*)(&As[ar*72 + ac +  0]) = av0;
    *(uint4*)(&As[ar*72 + ac +  8]) = av1;
    *(uint4*)(&As[ar*72 + ac + 16]) = av2;
    *(uint4*)(&As[ar*72 + ac + 24]) = av3;
    *(uint4*)(&Bs[bn*72 + bc + 0]) = bv0;
    *(uint4*)(&Bs[bn*72 + bc + 8]) = bv1;
    __syncthreads();
#pragma unroll
    for (int ks = 0; ks < 64; ks += 32){
      bs8 a0 = *(const bs8*)(&As[(w*32 +      l16)*72 + ks + q*8]);
      bs8 a1 = *(const bs8*)(&As[(w*32 + 16 + l16)*72 + ks + q*8]);
#pragma unroll
      for (int nf = 0; nf < 4; nf++){
        bs8 bf = *(const bs8*)(&Bs[(nf*16 + l16)*72 + ks + q*8]);
        acc[0][nf] = __builtin_amdgcn_mfma_f32_16x16x32_bf16(a0, bf, acc[0][nf], 0,0,0);
        acc[1][nf] = __builtin_amdgcn_mfma_f32_16x16x32_bf16(a1, bf, acc[1][nf], 0,0,0);
      }
    }
  }
  float bv[4];
#pragma unroll
  for (int nf = 0; nf < 4; nf++) bv[nf] = bias[nb*64 + nf*16 + l16];
#pragma unroll
  for (int mf = 0; mf < 2; mf++)
#pragma unroll
    for (int nf = 0; nf < 4; nf++)
#pragma unroll
      for (int i = 0; i < 4; i++){
        long row = mbase + w*32 + mf*16 + q*4 + i;
        long col = (long)nb*64 + nf*16 + l16;
        float v = acc[mf][nf][i] + bv[nf];
        if (doGelu) v = 0.5f*v*(1.f + erff(v*0.70710678118654752f));
        if (outBf16) ((unsigned short*)Cout)[row*strideC + col] = f2b(v);
        else         ((float*)Cout)[row*strideC + col] = v;
      }
}

// ---------------- LN over rows of 1024 (optionally double-LN), bf16 out ----------------
__global__ __launch_bounds__(256) void k_ln(
    const float* __restrict__ in,
    const float* __restrict__ g1, const float* __restrict__ b1,
    const float* __restrict__ g2, const float* __restrict__ b2, int two,
    unsigned short* __restrict__ out)
{
  __shared__ float scr[4];
  long row = blockIdx.x;
  int t = threadIdx.x;
  float4 v = *(const float4*)(in + row*1024 + t*4);
  float s = blk_sum(v.x+v.y+v.z+v.w, scr, t);
  float mean = s*(1.f/1024.f);
  float4 d; d.x=v.x-mean; d.y=v.y-mean; d.z=v.z-mean; d.w=v.w-mean;
  float ss = blk_sum(d.x*d.x+d.y*d.y+d.z*d.z+d.w*d.w, scr, t);
  float rs = rsqrtf(ss*(1.f/1024.f)+1e-5f);
  float4 g = *(const float4*)(g1+t*4); float4 bb = *(const float4*)(b1+t*4);
  float4 y; y.x=d.x*rs*g.x+bb.x; y.y=d.y*rs*g.y+bb.y; y.z=d.z*rs*g.z+bb.z; y.w=d.w*rs*g.w+bb.w;
  if (two){
    float s2 = blk_sum(y.x+y.y+y.z+y.w, scr, t);
    float m2 = s2*(1.f/1024.f);
    d.x=y.x-m2; d.y=y.y-m2; d.z=y.z-m2; d.w=y.w-m2;
    float ss2 = blk_sum(d.x*d.x+d.y*d.y+d.z*d.z+d.w*d.w, scr, t);
    float rs2 = rsqrtf(ss2*(1.f/1024.f)+1e-5f);
    g = *(const float4*)(g2+t*4); bb = *(const float4*)(b2+t*4);
    y.x=d.x*rs2*g.x+bb.x; y.y=d.y*rs2*g.y+bb.y; y.z=d.z*rs2*g.z+bb.z; y.w=d.w*rs2*g.w+bb.w;
  }
  uint2 o = make_uint2(pack2(y.x,y.y), pack2(y.z,y.w));
  *(uint2*)(out + row*1024 + t*4) = o;
}

// ---------------- K5: per-b temporal attention: scores2(MFMA)+softmax+ctx2 ----------------
__global__ __launch_bounds__(256) void k5_temporal(
    const unsigned short* __restrict__ kv,
    const unsigned short* __restrict__ weff2B, const float* __restrict__ ceff2,
    unsigned short* __restrict__ ctx2)
{
  __shared__ float S2[64*16];
  __shared__ float at2[64*16];
  int b = blockIdx.x;
  int t = threadIdx.x, w = t>>6, l = t&63, q = l>>4, l16 = l&15;
  const unsigned short* kvb = kv + (long)b*64*1024;
  {
    int p = w*16 + l16;
    const unsigned short* krow = kvb + (long)p*1024;
    fx4 acc = {0.f,0.f,0.f,0.f};
#pragma unroll 4
    for (int kk = 0; kk < 32; kk++){
      bs8 af = *(const bs8*)(krow + kk*32 + q*8);
      bs8 bf = *(const bs8*)(weff2B + (kk*64 + l)*8);
      acc = __builtin_amdgcn_mfma_f32_16x16x32_bf16(af, bf, acc, 0, 0, 0);
    }
    float cf = ceff2[l16];
#pragma unroll
    for (int i = 0; i < 4; i++) S2[(w*16 + q*4 + i)*16 + l16] = (acc[i]+cf)*0.125f;
  }
  __syncthreads();
  if (t < 16){
    float mx = -1e30f;
    for (int k = 0; k < 64; k++) mx = fmaxf(mx, S2[k*16+t]);
    float sm = 0.f;
    for (int k = 0; k < 64; k++){ float e = expf(S2[k*16+t]-mx); at2[k*16+t] = e; sm += e; }
    float inv = 1.f/sm;
    for (int k = 0; k < 64; k++) at2[k*16+t] *= inv;
  }
  __syncthreads();
  float4 a4[16];
#pragma unroll
  for (int h = 0; h < 16; h++){ a4[h].x=0.f; a4[h].y=0.f; a4[h].z=0.f; a4[h].w=0.f; }
  for (int p2 = 0; p2 < 64; p2++){
    ushort4 t4 = *(const ushort4*)(kvb + (long)p2*1024 + t*4);
    float x0=b2f(t4.x), x1=b2f(t4.y), x2=b2f(t4.z), x3=b2f(t4.w);
#pragma unroll
    for (int h = 0; h < 16; h++){
      float a = at2[p2*16+h];
      a4[h].x += a*x0; a4[h].y += a*x1; a4[h].z += a*x2; a4[h].w += a*x3;
    }
  }
  unsigned short* crow = ctx2 + ((long)b*16)*1024 + t*4;
#pragma unroll
  for (int h = 0; h < 16; h++){
    uint2 o = make_uint2(pack2(a4[h].x, a4[h].y), pack2(a4[h].z, a4[h].w));
    *(uint2*)(crow + (long)h*1024) = o;
  }
}

// ---------------- K9: logits = h1 @ w2 + b2 (N=23, vector) ----------------
__global__ __launch_bounds__(256) void k9_logits(
    const unsigned short* __restrict__ h1,
    const float* __restrict__ w2, const float* __restrict__ b2, float* __restrict__ out)
{
  __shared__ __align__(16) unsigned short hrow[4096];
  int b = blockIdx.x, t = threadIdx.x;
  *(uint4*)(&hrow[t*16])     = *(const uint4*)(h1 + (long)b*4096 + t*16);
  *(uint4*)(&hrow[t*16 + 8]) = *(const uint4*)(h1 + (long)b*4096 + t*16 + 8);
  __syncthreads();
  int c = t >> 3, l8 = t & 7;
  if (c < 23){
    float s = 0.f;
    for (int i = 0; i < 512; i++){
      int f = l8*512 + i;
      s += b2f(hrow[f]) * w2[(long)f*23 + c];
    }
    s += __shfl_xor(s, 1, 64); s += __shfl_xor(s, 2, 64); s += __shfl_xor(s, 4, 64);
    if (l8 == 0) out[b*23 + c] = s + b2[c];
  }
}

// ---------------- host ----------------
extern "C" void kernel_launch(void* const* d_in, const int* in_sizes, int n_in,
                              void* d_out, int out_size, void* d_ws, size_t ws_size,
                              hipStream_t stream)
{
  const float* x        = (const float*)d_in[0];
  const float* chq      = (const float*)d_in[1];
  const float* clq      = (const float*)d_in[2];
  const float* ch_in_w  = (const float*)d_in[3];
  const float* ch_in_b  = (const float*)d_in[4];
  const float* ch_out_w = (const float*)d_in[5];
  const float* ch_out_b = (const float*)d_in[6];
  const float* t_in_w   = (const float*)d_in[7];
  const float* t_in_b   = (const float*)d_in[8];
  const float* t_out_w  = (const float*)d_in[9];
  const float* t_out_b  = (const float*)d_in[10];
  const float* qn_g  = (const float*)d_in[11]; const float* qn_b  = (const float*)d_in[12];
  const float* cn_g  = (const float*)d_in[13]; const float* cn_b  = (const float*)d_in[14];
  const float* pnc_g = (const float*)d_in[15]; const float* pnc_b = (const float*)d_in[16];
  const float* pnp_g = (const float*)d_in[17]; const float* pnp_b = (const float*)d_in[18];
  const float* pon_g = (const float*)d_in[19]; const float* pon_b = (const float*)d_in[20];
  const float* w1 = (const float*)d_in[21]; const float* b1 = (const float*)d_in[22];
  const float* w2 = (const float*)d_in[23]; const float* b2 = (const float*)d_in[24];
  float* out = (float*)d_out;

  char* ws = (char*)d_ws;
  size_t off = 0;
  auto alloc = [&](size_t bytes)->char*{
    char* p = ws + off; off += (bytes + 255) & ~(size_t)255; return p;
  };
  float* q_f   = (float*)alloc(4096);
  float* cq_f  = (float*)alloc(4096);
  float* qh_f  = (float*)alloc(4096);
  float* qh2_f = (float*)alloc(4096);
  float* ceff  = (float*)alloc(256);
  float* ceff2 = (float*)alloc(256);
  unsigned short* weffB  = (unsigned short*)alloc(32768);
  unsigned short* weff2B = (unsigned short*)alloc(32768);
  unsigned short* WvT   = (unsigned short*)alloc(2097152);
  unsigned short* WoutT = (unsigned short*)alloc(2097152);
  unsigned short* Wv2T  = (unsigned short*)alloc(2097152);
  unsigned short* toutT = (unsigned short*)alloc(2097152);
  unsigned short* w1T   = (unsigned short*)alloc(8388608);
  unsigned short* pooled   = (unsigned short*)alloc((size_t)8192*1024*2);
  float*          fusedpre = (float*)alloc((size_t)8192*1024*4);
  unsigned short* kvw      = (unsigned short*)alloc((size_t)8192*1024*2);
  unsigned short* ctx2     = (unsigned short*)alloc((size_t)128*16384*2);
  unsigned short* pooled2  = (unsigned short*)alloc((size_t)128*1024*2);
  float*          pre2     = (float*)alloc((size_t)128*1024*4);
  unsigned short* zbuf     = (unsigned short*)alloc((size_t)128*1024*2);
  unsigned short* h1buf    = (unsigned short*)alloc((size_t)128*4096*2);
  size_t base = off;
  size_t avail = ws_size > base ? ws_size - base : 0;
  long rows = (long)(avail / ((size_t)16*1024*2));
  if (rows > 2048) rows = 2048;   // chunk so the ctx intermediate stays L3-resident
  rows &= ~127L;
  if (rows < 128) rows = 128;   // minimum chunk; assumes ws is at least ~91 MB
  unsigned short* ctxbuf = (unsigned short*)(ws + base);

  k_lnvec<<<dim3(2), dim3(256), 0, stream>>>(chq, qn_g, qn_b, q_f, clq, pnc_g, pnc_b, cq_f);
  k_gemv<<<dim3(64), dim3(256), 0, stream>>>(q_f, ch_in_w, ch_in_b, qh_f, cq_f, t_in_w, t_in_b, qh2_f);
  k_weff<<<dim3(128), dim3(256), 0, stream>>>(qh_f, ch_in_w, ch_in_b, weffB, ceff,
                                              qh2_f, t_in_w, t_in_b, weff2B, ceff2);
  k_transpose<<<dim3(8192), dim3(256), 0, stream>>>(
      ch_in_w + 2048, (long)3072, WvT,   1024,
      ch_out_w,       (long)1024, WoutT, 1024,
      t_in_w + 2048,  (long)3072, Wv2T,  1024,
      t_out_w,        (long)1024, toutT, 1024,
      w1,             (long)4096, w1T,   4096);

  for (long bp0 = 0; bp0 < 8192; bp0 += rows){
    long cnt = (8192 - bp0 < rows) ? (8192 - bp0) : rows;
    k1_attn<<<dim3((unsigned)cnt), dim3(256), 0, stream>>>(x, weffB, ceff, ctxbuf, (int)bp0);
    k_gemm<<<dim3((unsigned)(cnt/128), 16), dim3(256), 0, stream>>>(
        ctxbuf, (long)16384, (long)1024, WvT, 1024, ch_in_b + 2048,
        (void*)(pooled + bp0*1024), (long)1024, 1, 0, 1024);
  }
  k_gemm<<<dim3(64,16), dim3(256), 0, stream>>>(
      pooled, (long)1024, (long)0, WoutT, 1024, ch_out_b,
      (void*)fusedpre, (long)1024, 0, 0, 1024);
  k_ln<<<dim3(8192), dim3(256), 0, stream>>>(fusedpre, cn_g, cn_b, pnp_g, pnp_b, 1, kvw);
  k5_temporal<<<dim3(128), dim3(256), 0, stream>>>(kvw, weff2B, ceff2, ctx2);
  k_gemm<<<dim3(1,16), dim3(256), 0, stream>>>(
      ctx2, (long)16384, (long)1024, Wv2T, 1024, t_in_b + 2048,
      (void*)pooled2, (long)1024, 1, 0, 1024);
  k_gemm<<<dim3(1,16), dim3(256), 0, stream>>>(
      pooled2, (long)1024, (long)0, toutT, 1024, t_out_b,
      (void*)pre2, (long)1024, 0, 0, 1024);
  k_ln<<<dim3(128), dim3(256), 0, stream>>>(pre2, pon_g, pon_b, pon_g, pon_b, 0, zbuf);
  k_gemm<<<dim3(1,64), dim3(256), 0, stream>>>(
      zbuf, (long)1024, (long)0, w1T, 1024, b1,
      (void*)h1buf, (long)4096, 1, 1, 1024);
  k9_logits<<<dim3(128), dim3(256), 0, stream>>>(h1buf, w2, b2, out);
}